// Round 1
// baseline (3578.364 us; speedup 1.0000x reference)
//
#include <hip/hip_runtime.h>
#include <math.h>

#define NB    2
#define NPTS  8192
#define SSAMP 1024
#define NS    32
#define VV    8
#define CF    64
#define CIN   70
#define COUT  128
#define H1    32

__device__ __forceinline__ float gelu_f(float x){
  return 0.5f*x*(1.0f + erff(x*0.70710678118654752440f));
}

// ---------------------------------------------------------------------------
// Kernel 1: farthest point sampling. One block (1024 threads) per batch.
// Writes new_xyz (B,S,3) into the tail of d_out.
// Distances computed with rn intrinsics (no fma) to bit-match XLA.
// ---------------------------------------------------------------------------
__global__ __launch_bounds__(1024) void k_fps(const float* __restrict__ xyz,
                                              float* __restrict__ new_xyz){
  const int b = blockIdx.x;
  const int t = threadIdx.x;
  const float* X = xyz + (size_t)b * NPTS * 3;
  float px[8], py[8], pz[8], dmin[8];
#pragma unroll
  for (int k = 0; k < 8; k++){
    int i = t + k * 1024;
    px[k] = X[i*3+0]; py[k] = X[i*3+1]; pz[k] = X[i*3+2];
    dmin[k] = 3.4e38f;
  }
  __shared__ float cp[3];
  __shared__ float rv[16];
  __shared__ int   ri[16];
  int last = 0;
  const int lane = t & 63, wid = t >> 6;
  for (int s = 0; s < SSAMP; s++){
    if (t == (last & 1023)){
      int k = last >> 10;
      cp[0] = px[k]; cp[1] = py[k]; cp[2] = pz[k];
      float* o = new_xyz + ((size_t)b * SSAMP + s) * 3;
      o[0] = px[k]; o[1] = py[k]; o[2] = pz[k];
    }
    __syncthreads();
    float cx = cp[0], cy = cp[1], cz = cp[2];
    float best = -1.0f; int bi = 0x7fffffff;
#pragma unroll
    for (int k = 0; k < 8; k++){
      float dx = __fsub_rn(px[k], cx);
      float dy = __fsub_rn(py[k], cy);
      float dz = __fsub_rn(pz[k], cz);
      float d  = __fadd_rn(__fadd_rn(__fmul_rn(dx,dx), __fmul_rn(dy,dy)), __fmul_rn(dz,dz));
      d = fminf(dmin[k], d);
      dmin[k] = d;
      int i = t + k * 1024;
      if (d > best || (d == best && i < bi)){ best = d; bi = i; }
    }
#pragma unroll
    for (int off = 32; off >= 1; off >>= 1){
      float ov = __shfl_down(best, off);
      int   oi = __shfl_down(bi,   off);
      if (ov > best || (ov == best && oi < bi)){ best = ov; bi = oi; }
    }
    if (lane == 0){ rv[wid] = best; ri[wid] = bi; }
    __syncthreads();
    best = rv[0]; bi = ri[0];
#pragma unroll
    for (int j = 1; j < 16; j++){
      float ov = rv[j]; int oi = ri[j];
      if (ov > best || (ov == best && oi < bi)){ best = ov; bi = oi; }
    }
    last = bi;
  }
}

// ---------------------------------------------------------------------------
// Kernel 2: ball query + build gf (B,S,NS,CIN) = [grouped_xyz, local, feat].
// One wave per (b,s). Masked slots get zeros (matches reference semantics,
// which also zeroes downstream agg for them automatically).
// ---------------------------------------------------------------------------
__global__ __launch_bounds__(64) void k_ballq(const float* __restrict__ xyz,
                                              const float* __restrict__ feat,
                                              const float* __restrict__ new_xyz,
                                              float* __restrict__ gf){
  const int bs = blockIdx.x;          // b*S + s
  const int b  = bs >> 10;
  const int lane = threadIdx.x;
  const float* X = xyz  + (size_t)b * NPTS * 3;
  const float* F = feat + (size_t)b * NPTS * CF;
  const float cx = new_xyz[bs*3+0], cy = new_xyz[bs*3+1], cz = new_xyz[bs*3+2];
  __shared__ int gid[NS];
  if (lane < NS) gid[lane] = -1;
  __syncthreads();
  const float R2 = (float)(0.2 * 0.2);   // matches JAX double->f32 demotion
  int count = 0;
  for (int base = 0; base < NPTS && count < NS; base += 64){
    int i = base + lane;
    float x = X[i*3+0], y = X[i*3+1], z = X[i*3+2];
    float dx = __fsub_rn(cx,x), dy = __fsub_rn(cy,y), dz = __fsub_rn(cz,z);
    float d2 = __fadd_rn(__fadd_rn(__fmul_rn(dx,dx), __fmul_rn(dy,dy)), __fmul_rn(dz,dz));
    bool within = d2 < R2;
    unsigned long long m = __ballot(within);
    int pre  = __popcll(m & ((1ull << lane) - 1ull));
    int slot = count + pre;
    if (within && slot < NS) gid[slot] = i;
    count += __popcll(m);
  }
  __syncthreads();
  float* grow = gf + (size_t)bs * NS * CIN;
  for (int n = 0; n < NS; n++){
    int gi = gid[n];
    float* row = grow + n * CIN;
    if (gi < 0){
      row[lane] = 0.0f;
      if (lane < CIN - 64) row[64 + lane] = 0.0f;
    } else {
      float gx = X[gi*3+0], gy = X[gi*3+1], gz = X[gi*3+2];
      float v;
      if      (lane == 0) v = gx;
      else if (lane == 1) v = gy;
      else if (lane == 2) v = gz;
      else if (lane == 3) v = __fsub_rn(gx, cx);
      else if (lane == 4) v = __fsub_rn(gy, cy);
      else if (lane == 5) v = __fsub_rn(gz, cz);
      else                v = F[(size_t)gi * CF + (lane - 6)];
      row[lane] = v;
      if (lane < CIN - 64) row[64 + lane] = F[(size_t)gi * CF + 58 + lane];
    }
  }
}

// ---------------------------------------------------------------------------
// Kernel 3: BN1 statistics. thread <-> (row, v). Per-channel (H1=32)
// sum & sumsq accumulated via wave reduce + per-block double atomics.
// ---------------------------------------------------------------------------
__global__ __launch_bounds__(256) void k_stats1(const float* __restrict__ gf,
                                                const float* __restrict__ xyz,
                                                const int*   __restrict__ mc_idx,
                                                const float* __restrict__ W1_0,
                                                const float* __restrict__ b1_0,
                                                double* __restrict__ stats){
  __shared__ float W10[H1*13];
  __shared__ float b10[H1];
  __shared__ float mcs[NB][VV][3];
  __shared__ float part[4][64];
  const int t = threadIdx.x;
  for (int i = t; i < H1*13; i += 256) W10[i] = W1_0[i];
  if (t < H1) b10[t] = b1_0[t];
  if (t < NB*VV*3){
    int b_ = t / (VV*3), r = t % (VV*3), vv = r / 3, c = r % 3;
    mcs[b_][vv][c] = xyz[(size_t)b_ * NPTS * 3 + (size_t)mc_idx[vv] * 3 + c];
  }
  __syncthreads();
  const int tid = blockIdx.x * 256 + t;
  const int row = tid >> 3, v = tid & 7;
  const int b = row >> 15;                      // S*NS = 32768
  const float* g = gf + (size_t)row * CIN;
  float gx = g[0], gy = g[1], gz = g[2];
  float mx = mcs[b][v][0], my = mcs[b][v][1], mz = mcs[b][v][2];
  float ax = __fsub_rn(gx,mx), ay = __fsub_rn(gy,my), az = __fsub_rn(gz,mz);
  float eu = sqrtf(__fadd_rn(__fadd_rn(__fmul_rn(ax,ax), __fmul_rn(ay,ay)), __fmul_rn(az,az)));
  float rel[13] = {-ax,-ay,-az, ax,ay,az, eu, gx,gy,gz, mx,my,mz};
  float a1[H1];
#pragma unroll
  for (int h = 0; h < H1; h++){
    float acc = b10[h];
#pragma unroll
    for (int i = 0; i < 13; i++) acc = fmaf(rel[i], W10[h*13+i], acc);
    a1[h] = acc;
  }
  const int lane = t & 63, wid = t >> 6;
  for (int h = 0; h < H1; h++){
    float r1 = a1[h], r2 = a1[h]*a1[h];
#pragma unroll
    for (int off = 32; off >= 1; off >>= 1){
      r1 += __shfl_xor(r1, off);
      r2 += __shfl_xor(r2, off);
    }
    if (lane == 0){ part[wid][h] = r1; part[wid][h+32] = r2; }
  }
  __syncthreads();
  if (t < 64){
    float s = part[0][t] + part[1][t] + part[2][t] + part[3][t];
    atomicAdd(&stats[t], (double)s);
  }
}

__global__ void k_fin1(const double* __restrict__ st, const float* __restrict__ g1,
                       const float* __restrict__ be1, float* __restrict__ AB){
  int t = threadIdx.x;
  if (t < H1){
    double m   = st[t] / 524288.0;
    double var = st[t+32] / 524288.0 - m*m;
    double inv = 1.0 / sqrt(var + 1e-5);
    double A   = (double)g1[t] * inv;
    AB[t]      = (float)A;
    AB[t+H1]   = (float)((double)be1[t] - m*A);
  }
}

// ---------------------------------------------------------------------------
// Kernel 4: MLP1 (recompute a1, BN+gelu, x W1_1) + gumbel softmax + agg -> gf2
// lane <-> (row, v): 8 lanes per row; softmax over v via __shfl_xor(1,2,4).
// ---------------------------------------------------------------------------
__global__ __launch_bounds__(256) void k_mlp1(const float* __restrict__ gf,
                                              const float* __restrict__ gum,
                                              const float* __restrict__ xyz,
                                              const int*   __restrict__ mc_idx,
                                              const float* __restrict__ W1_0,
                                              const float* __restrict__ b1_0,
                                              const float* __restrict__ AB1,
                                              const float* __restrict__ W1_1,
                                              const float* __restrict__ b1_1,
                                              float* __restrict__ gf2){
  __shared__ float W10[H1*13];
  __shared__ float W11[CIN*H1];
  __shared__ float b10[H1], A1s[H1], B1s[H1];
  __shared__ float b11[CIN];
  __shared__ float mcs[NB][VV][3];
  const int t = threadIdx.x;
  for (int i = t; i < H1*13;  i += 256) W10[i] = W1_0[i];
  for (int i = t; i < CIN*H1; i += 256) W11[i] = W1_1[i];
  if (t < H1){ b10[t] = b1_0[t]; A1s[t] = AB1[t]; B1s[t] = AB1[t+H1]; }
  if (t < CIN) b11[t] = b1_1[t];
  if (t < NB*VV*3){
    int b_ = t / (VV*3), r = t % (VV*3), vv = r / 3, c = r % 3;
    mcs[b_][vv][c] = xyz[(size_t)b_ * NPTS * 3 + (size_t)mc_idx[vv] * 3 + c];
  }
  __syncthreads();
  const int tid = blockIdx.x * 256 + t;
  const int row = tid >> 3, v = tid & 7;
  const int b = row >> 15;
  const float* g = gf + (size_t)row * CIN;
  float gx = g[0], gy = g[1], gz = g[2];
  float mx = mcs[b][v][0], my = mcs[b][v][1], mz = mcs[b][v][2];
  float ax = __fsub_rn(gx,mx), ay = __fsub_rn(gy,my), az = __fsub_rn(gz,mz);
  float eu = sqrtf(__fadd_rn(__fadd_rn(__fmul_rn(ax,ax), __fmul_rn(ay,ay)), __fmul_rn(az,az)));
  float rel[13] = {-ax,-ay,-az, ax,ay,az, eu, gx,gy,gz, mx,my,mz};
  float a1g[H1];
#pragma unroll
  for (int h = 0; h < H1; h++){
    float acc = b10[h];
#pragma unroll
    for (int i = 0; i < 13; i++) acc = fmaf(rel[i], W10[h*13+i], acc);
    float x = fmaf(A1s[h], acc, B1s[h]);
    a1g[h] = gelu_f(x);
  }
  const float* gu = gum + (size_t)row * CIN * VV + v;
  for (int c = 0; c < CIN; c++){
    float a2 = b11[c];
#pragma unroll
    for (int h = 0; h < H1; h++) a2 = fmaf(a1g[h], W11[c*H1+h], a2);
    float gfv  = g[c];
    float prod = gfv * a2;
    float u    = gu[c*VV];
    float gg   = -__logf(-__logf(u));
    float tt   = prod + gg;
    float m8   = tt;
#pragma unroll
    for (int m = 1; m < 8; m <<= 1) m8 = fmaxf(m8, __shfl_xor(m8, m));
    float e  = __expf(tt - m8);
    float s1 = e, s2 = e * prod;
#pragma unroll
    for (int m = 1; m < 8; m <<= 1){ s1 += __shfl_xor(s1, m); s2 += __shfl_xor(s2, m); }
    if (v == 0) gf2[(size_t)row * CIN + c] = s2 / s1 + gfv;
  }
}

// ---------------------------------------------------------------------------
// Kernel 5: w_pre = gf2 @ W2_0^T + b2_0 (stored), res = gf @ Wr^T + br (stored),
// plus BN2 per-channel stats. thread <-> (cout, row-half); weights in regs.
// ---------------------------------------------------------------------------
__global__ __launch_bounds__(256) void k_wpre(const float* __restrict__ gf2,
                                              const float* __restrict__ gf,
                                              const float* __restrict__ W2_0,
                                              const float* __restrict__ b2_0,
                                              const float* __restrict__ Wr,
                                              const float* __restrict__ br,
                                              float* __restrict__ wpre,
                                              float* __restrict__ resb,
                                              double* __restrict__ stats2){
  const int t = threadIdx.x;
  const int c = t & 127, rh = t >> 7;
  float w0[CIN], wr[CIN];
#pragma unroll
  for (int i = 0; i < CIN; i++) w0[i] = W2_0[(size_t)c*CIN + i];
#pragma unroll
  for (int i = 0; i < CIN; i++) wr[i] = Wr[(size_t)c*CIN + i];
  const float bias0 = b2_0[c], biasr = br[c];
  const int base = blockIdx.x * 32;
  float s1 = 0.f, s2 = 0.f;
  for (int j = 0; j < 16; j++){
    int row = base + rh + 2*j;
    const float* g2r = gf2 + (size_t)row * CIN;
    const float* gr  = gf  + (size_t)row * CIN;
    float acc = bias0, accr = biasr;
#pragma unroll
    for (int i = 0; i < CIN; i++){
      float a = g2r[i], b = gr[i];
      acc  = fmaf(a, w0[i], acc);
      accr = fmaf(b, wr[i], accr);
    }
    wpre[(size_t)row*COUT + c] = acc;
    resb[(size_t)row*COUT + c] = accr;
    s1 += acc; s2 += acc*acc;
  }
  __shared__ float buf[256];
  buf[t] = s1; __syncthreads();
  if (t < 128) atomicAdd(&stats2[c], (double)(buf[t] + buf[t+128]));
  __syncthreads();
  buf[t] = s2; __syncthreads();
  if (t < 128) atomicAdd(&stats2[128+c], (double)(buf[t] + buf[t+128]));
}

__global__ void k_fin2(const double* __restrict__ st, const float* __restrict__ g2,
                       const float* __restrict__ be2, float* __restrict__ AB){
  int t = threadIdx.x;
  if (t < COUT){
    double m   = st[t] / 65536.0;
    double var = st[t+128] / 65536.0 - m*m;
    double inv = 1.0 / sqrt(var + 1e-5);
    double A   = (double)g2[t] * inv;
    AB[t]      = (float)A;
    AB[t+COUT] = (float)((double)be2[t] - m*A);
  }
}

// ---------------------------------------------------------------------------
// Kernel 6: final. gb = gelu(BN2(w_pre)); w2 = gb @ W2_1^T + b2_1;
// new_f = gelu(w2 + res); out = max_n + sum_n. Block handles 2 (b,s).
// W2_1 row per thread in registers; gb exchanged through LDS.
// ---------------------------------------------------------------------------
__global__ __launch_bounds__(512) void k_final(const float* __restrict__ wpre,
                                               const float* __restrict__ resb,
                                               const float* __restrict__ W2_1,
                                               const float* __restrict__ b2_1,
                                               const float* __restrict__ AB2,
                                               float* __restrict__ out){
  __shared__ float gbuf[4][COUT];
  __shared__ float pm[512], ps[512];
  const int t = threadIdx.x;
  const int o = t & 127, g = t >> 7;
  float w21[COUT];
#pragma unroll
  for (int k = 0; k < COUT; k++) w21[k] = W2_1[(size_t)o*COUT + k];
  const float A2 = AB2[o], B2 = AB2[COUT+o], b21 = b2_1[o];
  const int bs = blockIdx.x * 2 + (g >> 1);
  const int rp = g & 1;
  float vmax = -3.4e38f, vsum = 0.f;
  for (int j = 0; j < 16; j++){
    int n = rp + 2*j;
    int row = bs * NS + n;
    float w  = wpre[(size_t)row*COUT + o];
    float x  = fmaf(A2, w, B2);
    gbuf[g][o] = gelu_f(x);
    __syncthreads();
    float w2 = b21;
#pragma unroll
    for (int k = 0; k < COUT; k++) w2 = fmaf(gbuf[g][k], w21[k], w2);
    float y  = w2 + resb[(size_t)row*COUT + o];
    float nf = gelu_f(y);
    vmax = fmaxf(vmax, nf);
    vsum += nf;
    __syncthreads();
  }
  pm[t] = vmax; ps[t] = vsum;
  __syncthreads();
  if (rp == 0){
    float m = fmaxf(pm[t], pm[t+128]);
    float s = ps[t] + ps[t+128];
    out[(size_t)bs*COUT + o] = m + s;
  }
}

// ---------------------------------------------------------------------------
extern "C" void kernel_launch(void* const* d_in, const int* in_sizes, int n_in,
                              void* d_out, int out_size, void* d_ws, size_t ws_size,
                              hipStream_t stream) {
  (void)in_sizes; (void)n_in; (void)out_size; (void)ws_size;
  const float* xyz   = (const float*)d_in[0];
  const float* f     = (const float*)d_in[1];
  const int*   mcid  = (const int*)  d_in[2];
  const float* gum   = (const float*)d_in[3];
  const float* W1_0  = (const float*)d_in[4];
  const float* b1_0  = (const float*)d_in[5];
  const float* g1_0  = (const float*)d_in[6];
  const float* be1_0 = (const float*)d_in[7];
  const float* W1_1  = (const float*)d_in[8];
  const float* b1_1  = (const float*)d_in[9];
  const float* W2_0  = (const float*)d_in[10];
  const float* b2_0  = (const float*)d_in[11];
  const float* g2_0  = (const float*)d_in[12];
  const float* be2_0 = (const float*)d_in[13];
  const float* W2_1  = (const float*)d_in[14];
  const float* b2_1  = (const float*)d_in[15];
  const float* Wr    = (const float*)d_in[16];
  const float* br    = (const float*)d_in[17];

  float* out     = (float*)d_out;
  float* new_xyz = out + (size_t)NB * SSAMP * COUT;   // tail of d_out

  char*   ws    = (char*)d_ws;
  double* stats = (double*)ws;                 // [0..63] BN1, [64..319] BN2
  float*  AB1   = (float*)(ws + 2560);         // 32 A + 32 B
  float*  AB2   = AB1 + 64;                    // 128 A + 128 B
  float*  gfb   = (float*)(ws + 4096);
  const size_t ROWS = (size_t)NB * SSAMP * NS; // 65536
  float*  gf2   = gfb + ROWS * CIN;
  float*  wpre  = gf2 + ROWS * CIN;
  float*  resb  = wpre + ROWS * COUT;

  hipMemsetAsync(d_ws, 0, 2560, stream);

  k_fps   <<<NB,              1024, 0, stream>>>(xyz, new_xyz);
  k_ballq <<<NB*SSAMP,        64,   0, stream>>>(xyz, f, new_xyz, gfb);
  k_stats1<<<2048,            256,  0, stream>>>(gfb, xyz, mcid, W1_0, b1_0, stats);
  k_fin1  <<<1,               64,   0, stream>>>(stats, g1_0, be1_0, AB1);
  k_mlp1  <<<2048,            256,  0, stream>>>(gfb, gum, xyz, mcid, W1_0, b1_0, AB1, W1_1, b1_1, gf2);
  k_wpre  <<<2048,            256,  0, stream>>>(gf2, gfb, W2_0, b2_0, Wr, br, wpre, resb, stats + 64);
  k_fin2  <<<1,               128,  0, stream>>>(stats + 64, g2_0, be2_0, AB2);
  k_final <<<1024,            512,  0, stream>>>(wpre, resb, W2_1, b2_1, AB2, out);
}

// Round 2
// 2182.251 us; speedup vs baseline: 1.6398x; 1.6398x over previous
//
#include <hip/hip_runtime.h>
#include <math.h>

#define NB    2
#define NPTS  8192
#define SSAMP 1024
#define NS    32
#define VV    8
#define CF    64
#define CIN   70
#define COUT  128
#define H1    32

__device__ __forceinline__ float gelu_f(float x){
  return 0.5f*x*(1.0f + erff(x*0.70710678118654752440f));
}

// ---------------------------------------------------------------------------
// Kernel 1: farthest point sampling, 1-barrier-per-step version.
// One block (1024 threads) per batch. xyz staged in LDS (96KB) for the
// center-broadcast read; (dist,idx) packed into a monotone u64 key
// (dist bits << 32 | ~idx) so argmax+tie-break is a single u64 max chain.
// Partials double-buffered so a single __syncthreads per step suffices.
// Distances use rn intrinsics (no fma) to bit-match XLA.
// ---------------------------------------------------------------------------
__global__ __launch_bounds__(1024) void k_fps(const float* __restrict__ xyz,
                                              float* __restrict__ new_xyz){
  extern __shared__ unsigned char dynls[];
  float* sx = (float*)dynls;
  float* sy = sx + NPTS;
  float* sz = sy + NPTS;
  unsigned long long* part = (unsigned long long*)(sz + NPTS); // [2][16]

  const int b = blockIdx.x;
  const int t = threadIdx.x;
  const float* X = xyz + (size_t)b * NPTS * 3;
  float px[8], py[8], pz[8], dmin[8];
  unsigned nio[8];
#pragma unroll
  for (int k = 0; k < 8; k++){
    int i = t + k * 1024;
    float x = X[i*3+0], y = X[i*3+1], z = X[i*3+2];
    px[k] = x; py[k] = y; pz[k] = z;
    sx[i] = x; sy[i] = y; sz[i] = z;
    dmin[k] = 3.4e38f;
    nio[k] = ~(unsigned)i;
  }
  __syncthreads();

  int last = 0;
  const int lane = t & 63, wid = t >> 6;
  int pb = 0;
  float* orow = new_xyz + (size_t)b * SSAMP * 3;
  for (int s = 0; s < SSAMP; s++){
    float cx = sx[last], cy = sy[last], cz = sz[last];
    if (t == 0){ orow[0] = cx; orow[1] = cy; orow[2] = cz; orow += 3; }
    unsigned long long bk = 0ull;
#pragma unroll
    for (int k = 0; k < 8; k++){
      float dx = __fsub_rn(px[k], cx);
      float dy = __fsub_rn(py[k], cy);
      float dz = __fsub_rn(pz[k], cz);
      float d  = __fadd_rn(__fadd_rn(__fmul_rn(dx,dx), __fmul_rn(dy,dy)), __fmul_rn(dz,dz));
      d = fminf(dmin[k], d);
      dmin[k] = d;
      unsigned long long key = ((unsigned long long)__float_as_uint(d) << 32) | (unsigned long long)nio[k];
      bk = (key > bk) ? key : bk;
    }
#pragma unroll
    for (int off = 32; off >= 1; off >>= 1){
      unsigned long long o = __shfl_down(bk, off);
      bk = (o > bk) ? o : bk;
    }
    if (lane == 0) part[pb*16 + wid] = bk;
    __syncthreads();
    unsigned long long v[16];
#pragma unroll
    for (int j = 0; j < 16; j++) v[j] = part[pb*16 + j];
#pragma unroll
    for (int st = 8; st >= 1; st >>= 1){
#pragma unroll
      for (int j = 0; j < 8; j++){
        if (j < st) v[j] = (v[j] > v[j+st]) ? v[j] : v[j+st];
      }
    }
    last = (int)(~(unsigned)(v[0] & 0xFFFFFFFFull));
    pb ^= 1;
  }
}

// ---------------------------------------------------------------------------
// Kernel 2: ball query + build gf (B,S,NS,CIN) = [grouped_xyz, local, feat].
// One wave per (b,s). Masked slots get zeros (matches reference semantics,
// which also zeroes downstream agg for them automatically).
// ---------------------------------------------------------------------------
__global__ __launch_bounds__(64) void k_ballq(const float* __restrict__ xyz,
                                              const float* __restrict__ feat,
                                              const float* __restrict__ new_xyz,
                                              float* __restrict__ gf){
  const int bs = blockIdx.x;          // b*S + s
  const int b  = bs >> 10;
  const int lane = threadIdx.x;
  const float* X = xyz  + (size_t)b * NPTS * 3;
  const float* F = feat + (size_t)b * NPTS * CF;
  const float cx = new_xyz[bs*3+0], cy = new_xyz[bs*3+1], cz = new_xyz[bs*3+2];
  __shared__ int gid[NS];
  if (lane < NS) gid[lane] = -1;
  __syncthreads();
  const float R2 = (float)(0.2 * 0.2);   // matches JAX double->f32 demotion
  int count = 0;
  for (int base = 0; base < NPTS && count < NS; base += 64){
    int i = base + lane;
    float x = X[i*3+0], y = X[i*3+1], z = X[i*3+2];
    float dx = __fsub_rn(cx,x), dy = __fsub_rn(cy,y), dz = __fsub_rn(cz,z);
    float d2 = __fadd_rn(__fadd_rn(__fmul_rn(dx,dx), __fmul_rn(dy,dy)), __fmul_rn(dz,dz));
    bool within = d2 < R2;
    unsigned long long m = __ballot(within);
    int pre  = __popcll(m & ((1ull << lane) - 1ull));
    int slot = count + pre;
    if (within && slot < NS) gid[slot] = i;
    count += __popcll(m);
  }
  __syncthreads();
  float* grow = gf + (size_t)bs * NS * CIN;
  for (int n = 0; n < NS; n++){
    int gi = gid[n];
    float* row = grow + n * CIN;
    if (gi < 0){
      row[lane] = 0.0f;
      if (lane < CIN - 64) row[64 + lane] = 0.0f;
    } else {
      float gx = X[gi*3+0], gy = X[gi*3+1], gz = X[gi*3+2];
      float v;
      if      (lane == 0) v = gx;
      else if (lane == 1) v = gy;
      else if (lane == 2) v = gz;
      else if (lane == 3) v = __fsub_rn(gx, cx);
      else if (lane == 4) v = __fsub_rn(gy, cy);
      else if (lane == 5) v = __fsub_rn(gz, cz);
      else                v = F[(size_t)gi * CF + (lane - 6)];
      row[lane] = v;
      if (lane < CIN - 64) row[64 + lane] = F[(size_t)gi * CF + 58 + lane];
    }
  }
}

// ---------------------------------------------------------------------------
// Kernel 3: BN1 statistics. thread <-> (row, v). Per-channel (H1=32)
// sum & sumsq accumulated via wave reduce + per-block double atomics.
// ---------------------------------------------------------------------------
__global__ __launch_bounds__(256) void k_stats1(const float* __restrict__ gf,
                                                const float* __restrict__ xyz,
                                                const int*   __restrict__ mc_idx,
                                                const float* __restrict__ W1_0,
                                                const float* __restrict__ b1_0,
                                                double* __restrict__ stats){
  __shared__ float W10[H1*13];
  __shared__ float b10[H1];
  __shared__ float mcs[NB][VV][3];
  __shared__ float part[4][64];
  const int t = threadIdx.x;
  for (int i = t; i < H1*13; i += 256) W10[i] = W1_0[i];
  if (t < H1) b10[t] = b1_0[t];
  if (t < NB*VV*3){
    int b_ = t / (VV*3), r = t % (VV*3), vv = r / 3, c = r % 3;
    mcs[b_][vv][c] = xyz[(size_t)b_ * NPTS * 3 + (size_t)mc_idx[vv] * 3 + c];
  }
  __syncthreads();
  const int tid = blockIdx.x * 256 + t;
  const int row = tid >> 3, v = tid & 7;
  const int b = row >> 15;                      // S*NS = 32768
  const float* g = gf + (size_t)row * CIN;
  float gx = g[0], gy = g[1], gz = g[2];
  float mx = mcs[b][v][0], my = mcs[b][v][1], mz = mcs[b][v][2];
  float ax = __fsub_rn(gx,mx), ay = __fsub_rn(gy,my), az = __fsub_rn(gz,mz);
  float eu = sqrtf(__fadd_rn(__fadd_rn(__fmul_rn(ax,ax), __fmul_rn(ay,ay)), __fmul_rn(az,az)));
  float rel[13] = {-ax,-ay,-az, ax,ay,az, eu, gx,gy,gz, mx,my,mz};
  float a1[H1];
#pragma unroll
  for (int h = 0; h < H1; h++){
    float acc = b10[h];
#pragma unroll
    for (int i = 0; i < 13; i++) acc = fmaf(rel[i], W10[h*13+i], acc);
    a1[h] = acc;
  }
  const int lane = t & 63, wid = t >> 6;
  for (int h = 0; h < H1; h++){
    float r1 = a1[h], r2 = a1[h]*a1[h];
#pragma unroll
    for (int off = 32; off >= 1; off >>= 1){
      r1 += __shfl_xor(r1, off);
      r2 += __shfl_xor(r2, off);
    }
    if (lane == 0){ part[wid][h] = r1; part[wid][h+32] = r2; }
  }
  __syncthreads();
  if (t < 64){
    float s = part[0][t] + part[1][t] + part[2][t] + part[3][t];
    atomicAdd(&stats[t], (double)s);
  }
}

__global__ void k_fin1(const double* __restrict__ st, const float* __restrict__ g1,
                       const float* __restrict__ be1, float* __restrict__ AB){
  int t = threadIdx.x;
  if (t < H1){
    double m   = st[t] / 524288.0;
    double var = st[t+32] / 524288.0 - m*m;
    double inv = 1.0 / sqrt(var + 1e-5);
    double A   = (double)g1[t] * inv;
    AB[t]      = (float)A;
    AB[t+H1]   = (float)((double)be1[t] - m*A);
  }
}

// ---------------------------------------------------------------------------
// Kernel 4: MLP1 (recompute a1, BN+gelu, x W1_1) + gumbel softmax + agg -> gf2
// lane <-> (row, v): 8 lanes per row; softmax over v via __shfl_xor(1,2,4).
// ---------------------------------------------------------------------------
__global__ __launch_bounds__(256) void k_mlp1(const float* __restrict__ gf,
                                              const float* __restrict__ gum,
                                              const float* __restrict__ xyz,
                                              const int*   __restrict__ mc_idx,
                                              const float* __restrict__ W1_0,
                                              const float* __restrict__ b1_0,
                                              const float* __restrict__ AB1,
                                              const float* __restrict__ W1_1,
                                              const float* __restrict__ b1_1,
                                              float* __restrict__ gf2){
  __shared__ float W10[H1*13];
  __shared__ float W11[CIN*H1];
  __shared__ float b10[H1], A1s[H1], B1s[H1];
  __shared__ float b11[CIN];
  __shared__ float mcs[NB][VV][3];
  const int t = threadIdx.x;
  for (int i = t; i < H1*13;  i += 256) W10[i] = W1_0[i];
  for (int i = t; i < CIN*H1; i += 256) W11[i] = W1_1[i];
  if (t < H1){ b10[t] = b1_0[t]; A1s[t] = AB1[t]; B1s[t] = AB1[t+H1]; }
  if (t < CIN) b11[t] = b1_1[t];
  if (t < NB*VV*3){
    int b_ = t / (VV*3), r = t % (VV*3), vv = r / 3, c = r % 3;
    mcs[b_][vv][c] = xyz[(size_t)b_ * NPTS * 3 + (size_t)mc_idx[vv] * 3 + c];
  }
  __syncthreads();
  const int tid = blockIdx.x * 256 + t;
  const int row = tid >> 3, v = tid & 7;
  const int b = row >> 15;
  const float* g = gf + (size_t)row * CIN;
  float gx = g[0], gy = g[1], gz = g[2];
  float mx = mcs[b][v][0], my = mcs[b][v][1], mz = mcs[b][v][2];
  float ax = __fsub_rn(gx,mx), ay = __fsub_rn(gy,my), az = __fsub_rn(gz,mz);
  float eu = sqrtf(__fadd_rn(__fadd_rn(__fmul_rn(ax,ax), __fmul_rn(ay,ay)), __fmul_rn(az,az)));
  float rel[13] = {-ax,-ay,-az, ax,ay,az, eu, gx,gy,gz, mx,my,mz};
  float a1g[H1];
#pragma unroll
  for (int h = 0; h < H1; h++){
    float acc = b10[h];
#pragma unroll
    for (int i = 0; i < 13; i++) acc = fmaf(rel[i], W10[h*13+i], acc);
    float x = fmaf(A1s[h], acc, B1s[h]);
    a1g[h] = gelu_f(x);
  }
  const float* gu = gum + (size_t)row * CIN * VV + v;
  for (int c = 0; c < CIN; c++){
    float a2 = b11[c];
#pragma unroll
    for (int h = 0; h < H1; h++) a2 = fmaf(a1g[h], W11[c*H1+h], a2);
    float gfv  = g[c];
    float prod = gfv * a2;
    float u    = gu[c*VV];
    float gg   = -__logf(-__logf(u));
    float tt   = prod + gg;
    float m8   = tt;
#pragma unroll
    for (int m = 1; m < 8; m <<= 1) m8 = fmaxf(m8, __shfl_xor(m8, m));
    float e  = __expf(tt - m8);
    float s1 = e, s2 = e * prod;
#pragma unroll
    for (int m = 1; m < 8; m <<= 1){ s1 += __shfl_xor(s1, m); s2 += __shfl_xor(s2, m); }
    if (v == 0) gf2[(size_t)row * CIN + c] = s2 / s1 + gfv;
  }
}

// ---------------------------------------------------------------------------
// Kernel 5: w_pre = gf2 @ W2_0^T + b2_0 (stored), res = gf @ Wr^T + br (stored),
// plus BN2 per-channel stats. thread <-> (cout, row-half); weights in regs.
// ---------------------------------------------------------------------------
__global__ __launch_bounds__(256) void k_wpre(const float* __restrict__ gf2,
                                              const float* __restrict__ gf,
                                              const float* __restrict__ W2_0,
                                              const float* __restrict__ b2_0,
                                              const float* __restrict__ Wr,
                                              const float* __restrict__ br,
                                              float* __restrict__ wpre,
                                              float* __restrict__ resb,
                                              double* __restrict__ stats2){
  const int t = threadIdx.x;
  const int c = t & 127, rh = t >> 7;
  float w0[CIN], wr[CIN];
#pragma unroll
  for (int i = 0; i < CIN; i++) w0[i] = W2_0[(size_t)c*CIN + i];
#pragma unroll
  for (int i = 0; i < CIN; i++) wr[i] = Wr[(size_t)c*CIN + i];
  const float bias0 = b2_0[c], biasr = br[c];
  const int base = blockIdx.x * 32;
  float s1 = 0.f, s2 = 0.f;
  for (int j = 0; j < 16; j++){
    int row = base + rh + 2*j;
    const float* g2r = gf2 + (size_t)row * CIN;
    const float* gr  = gf  + (size_t)row * CIN;
    float acc = bias0, accr = biasr;
#pragma unroll
    for (int i = 0; i < CIN; i++){
      float a = g2r[i], b = gr[i];
      acc  = fmaf(a, w0[i], acc);
      accr = fmaf(b, wr[i], accr);
    }
    wpre[(size_t)row*COUT + c] = acc;
    resb[(size_t)row*COUT + c] = accr;
    s1 += acc; s2 += acc*acc;
  }
  __shared__ float buf[256];
  buf[t] = s1; __syncthreads();
  if (t < 128) atomicAdd(&stats2[c], (double)(buf[t] + buf[t+128]));
  __syncthreads();
  buf[t] = s2; __syncthreads();
  if (t < 128) atomicAdd(&stats2[128+c], (double)(buf[t] + buf[t+128]));
}

__global__ void k_fin2(const double* __restrict__ st, const float* __restrict__ g2,
                       const float* __restrict__ be2, float* __restrict__ AB){
  int t = threadIdx.x;
  if (t < COUT){
    double m   = st[t] / 65536.0;
    double var = st[t+128] / 65536.0 - m*m;
    double inv = 1.0 / sqrt(var + 1e-5);
    double A   = (double)g2[t] * inv;
    AB[t]      = (float)A;
    AB[t+COUT] = (float)((double)be2[t] - m*A);
  }
}

// ---------------------------------------------------------------------------
// Kernel 6: final. gb = gelu(BN2(w_pre)); w2 = gb @ W2_1^T + b2_1;
// new_f = gelu(w2 + res); out = max_n + sum_n. Block handles 2 (b,s).
// W2_1 row per thread in registers; gb exchanged through LDS.
// ---------------------------------------------------------------------------
__global__ __launch_bounds__(512) void k_final(const float* __restrict__ wpre,
                                               const float* __restrict__ resb,
                                               const float* __restrict__ W2_1,
                                               const float* __restrict__ b2_1,
                                               const float* __restrict__ AB2,
                                               float* __restrict__ out){
  __shared__ float gbuf[4][COUT];
  __shared__ float pm[512], ps[512];
  const int t = threadIdx.x;
  const int o = t & 127, g = t >> 7;
  float w21[COUT];
#pragma unroll
  for (int k = 0; k < COUT; k++) w21[k] = W2_1[(size_t)o*COUT + k];
  const float A2 = AB2[o], B2 = AB2[COUT+o], b21 = b2_1[o];
  const int bs = blockIdx.x * 2 + (g >> 1);
  const int rp = g & 1;
  float vmax = -3.4e38f, vsum = 0.f;
  for (int j = 0; j < 16; j++){
    int n = rp + 2*j;
    int row = bs * NS + n;
    float w  = wpre[(size_t)row*COUT + o];
    float x  = fmaf(A2, w, B2);
    gbuf[g][o] = gelu_f(x);
    __syncthreads();
    float w2 = b21;
#pragma unroll
    for (int k = 0; k < COUT; k++) w2 = fmaf(gbuf[g][k], w21[k], w2);
    float y  = w2 + resb[(size_t)row*COUT + o];
    float nf = gelu_f(y);
    vmax = fmaxf(vmax, nf);
    vsum += nf;
    __syncthreads();
  }
  pm[t] = vmax; ps[t] = vsum;
  __syncthreads();
  if (rp == 0){
    float m = fmaxf(pm[t], pm[t+128]);
    float s = ps[t] + ps[t+128];
    out[(size_t)bs*COUT + o] = m + s;
  }
}

// ---------------------------------------------------------------------------
extern "C" void kernel_launch(void* const* d_in, const int* in_sizes, int n_in,
                              void* d_out, int out_size, void* d_ws, size_t ws_size,
                              hipStream_t stream) {
  (void)in_sizes; (void)n_in; (void)out_size; (void)ws_size;
  const float* xyz   = (const float*)d_in[0];
  const float* f     = (const float*)d_in[1];
  const int*   mcid  = (const int*)  d_in[2];
  const float* gum   = (const float*)d_in[3];
  const float* W1_0  = (const float*)d_in[4];
  const float* b1_0  = (const float*)d_in[5];
  const float* g1_0  = (const float*)d_in[6];
  const float* be1_0 = (const float*)d_in[7];
  const float* W1_1  = (const float*)d_in[8];
  const float* b1_1  = (const float*)d_in[9];
  const float* W2_0  = (const float*)d_in[10];
  const float* b2_0  = (const float*)d_in[11];
  const float* g2_0  = (const float*)d_in[12];
  const float* be2_0 = (const float*)d_in[13];
  const float* W2_1  = (const float*)d_in[14];
  const float* b2_1  = (const float*)d_in[15];
  const float* Wr    = (const float*)d_in[16];
  const float* br    = (const float*)d_in[17];

  float* out     = (float*)d_out;
  float* new_xyz = out + (size_t)NB * SSAMP * COUT;   // tail of d_out

  char*   ws    = (char*)d_ws;
  double* stats = (double*)ws;                 // [0..63] BN1, [64..319] BN2
  float*  AB1   = (float*)(ws + 2560);         // 32 A + 32 B
  float*  AB2   = AB1 + 64;                    // 128 A + 128 B
  float*  gfb   = (float*)(ws + 4096);
  const size_t ROWS = (size_t)NB * SSAMP * NS; // 65536
  float*  gf2   = gfb + ROWS * CIN;
  float*  wpre  = gf2 + ROWS * CIN;
  float*  resb  = wpre + ROWS * COUT;

  hipMemsetAsync(d_ws, 0, 2560, stream);

  const size_t fps_lds = (size_t)NPTS * 3 * sizeof(float) + 2 * 16 * sizeof(unsigned long long);
  k_fps   <<<NB,              1024, fps_lds, stream>>>(xyz, new_xyz);
  k_ballq <<<NB*SSAMP,        64,   0, stream>>>(xyz, f, new_xyz, gfb);
  k_stats1<<<2048,            256,  0, stream>>>(gfb, xyz, mcid, W1_0, b1_0, stats);
  k_fin1  <<<1,               64,   0, stream>>>(stats, g1_0, be1_0, AB1);
  k_mlp1  <<<2048,            256,  0, stream>>>(gfb, gum, xyz, mcid, W1_0, b1_0, AB1, W1_1, b1_1, gf2);
  k_wpre  <<<2048,            256,  0, stream>>>(gf2, gfb, W2_0, b2_0, Wr, br, wpre, resb, stats + 64);
  k_fin2  <<<1,               128,  0, stream>>>(stats + 64, g2_0, be2_0, AB2);
  k_final <<<1024,            512,  0, stream>>>(wpre, resb, W2_1, b2_1, AB2, out);
}

// Round 3
// 2048.701 us; speedup vs baseline: 1.7467x; 1.0652x over previous
//
#include <hip/hip_runtime.h>
#include <math.h>

#define NB    2
#define NPTS  8192
#define SSAMP 1024
#define NS    32
#define VV    8
#define CF    64
#define CIN   70
#define COUT  128
#define H1    32

__device__ __forceinline__ float gelu_f(float x){
  return 0.5f*x*(1.0f + erff(x*0.70710678118654752440f));
}

// ---------------------------------------------------------------------------
// Kernel 1: farthest point sampling, v3.
// 256 threads (4 waves) per batch, 32 points/thread in registers.
// Per step: LDS broadcast center (12B interleaved read) -> 32 reg-resident
// dist updates with (cmp,cndmask,max) argmax tracking -> 6-level wave
// shuffle reduce of (f32,idx) with first-occurrence tie-break -> 4 u64
// partials in double-buffered LDS -> ONE barrier -> redundant 2-level tree.
// Distances use rn intrinsics (no fma) to bit-match the reference.
// ---------------------------------------------------------------------------
__global__ __launch_bounds__(256) void k_fps(const float* __restrict__ xyz,
                                             float* __restrict__ new_xyz){
  extern __shared__ unsigned char dynls[];
  float* sxyz = (float*)dynls;                                   // [NPTS*3] interleaved
  unsigned long long* part = (unsigned long long*)(sxyz + NPTS*3); // [2][4]

  const int b = blockIdx.x;
  const int t = threadIdx.x;
  const float* X = xyz + (size_t)b * NPTS * 3;
  float px[32], py[32], pz[32], dmin[32];
#pragma unroll
  for (int k = 0; k < 32; k++){
    int i = t + k * 256;
    float x = X[i*3+0], y = X[i*3+1], z = X[i*3+2];
    px[k] = x; py[k] = y; pz[k] = z;
    sxyz[i*3+0] = x; sxyz[i*3+1] = y; sxyz[i*3+2] = z;
    dmin[k] = 3.4e38f;
  }
  __syncthreads();

  int last = 0;
  const int lane = t & 63, wid = t >> 6;
  int pb = 0;
  float* orow = new_xyz + (size_t)b * SSAMP * 3;
  for (int s = 0; s < SSAMP; s++){
    float cx = sxyz[last*3+0], cy = sxyz[last*3+1], cz = sxyz[last*3+2];
    if (t == 0){ orow[0] = cx; orow[1] = cy; orow[2] = cz; orow += 3; }
    float best = -1.0f; int bk = 0;
#pragma unroll
    for (int k = 0; k < 32; k++){
      float dx = __fsub_rn(px[k], cx);
      float dy = __fsub_rn(py[k], cy);
      float dz = __fsub_rn(pz[k], cz);
      float d  = __fadd_rn(__fadd_rn(__fmul_rn(dx,dx), __fmul_rn(dy,dy)), __fmul_rn(dz,dz));
      d = fminf(dmin[k], d);
      dmin[k] = d;
      bk   = (d > best) ? k : bk;      // ascending k + strict > = first max
      best = fmaxf(best, d);
    }
    int bi = t | (bk << 8);            // true point index (t<256)
#pragma unroll
    for (int off = 32; off >= 1; off >>= 1){
      float ov = __shfl_down(best, off);
      int   oi = __shfl_down(bi,   off);
      bool take = (ov > best) || (ov == best && oi < bi);
      best = take ? ov : best;
      bi   = take ? oi : bi;
    }
    if (lane == 0){
      part[pb*4 + wid] = ((unsigned long long)__float_as_uint(best) << 32)
                       | (unsigned long long)(~(unsigned)bi);
    }
    __syncthreads();
    unsigned long long v0 = part[pb*4 + 0];
    unsigned long long v1 = part[pb*4 + 1];
    unsigned long long v2 = part[pb*4 + 2];
    unsigned long long v3 = part[pb*4 + 3];
    unsigned long long m0 = (v0 > v1) ? v0 : v1;
    unsigned long long m1 = (v2 > v3) ? v2 : v3;
    unsigned long long m  = (m0 > m1) ? m0 : m1;
    last = (int)(~(unsigned)(m & 0xFFFFFFFFull));
    pb ^= 1;
  }
}

// ---------------------------------------------------------------------------
// Kernel 2: ball query + build gf (B,S,NS,CIN) = [grouped_xyz, local, feat].
// One wave per (b,s). Masked slots get zeros (matches reference semantics,
// which also zeroes downstream agg for them automatically).
// ---------------------------------------------------------------------------
__global__ __launch_bounds__(64) void k_ballq(const float* __restrict__ xyz,
                                              const float* __restrict__ feat,
                                              const float* __restrict__ new_xyz,
                                              float* __restrict__ gf){
  const int bs = blockIdx.x;          // b*S + s
  const int b  = bs >> 10;
  const int lane = threadIdx.x;
  const float* X = xyz  + (size_t)b * NPTS * 3;
  const float* F = feat + (size_t)b * NPTS * CF;
  const float cx = new_xyz[bs*3+0], cy = new_xyz[bs*3+1], cz = new_xyz[bs*3+2];
  __shared__ int gid[NS];
  if (lane < NS) gid[lane] = -1;
  __syncthreads();
  const float R2 = (float)(0.2 * 0.2);   // matches JAX double->f32 demotion
  int count = 0;
  for (int base = 0; base < NPTS && count < NS; base += 64){
    int i = base + lane;
    float x = X[i*3+0], y = X[i*3+1], z = X[i*3+2];
    float dx = __fsub_rn(cx,x), dy = __fsub_rn(cy,y), dz = __fsub_rn(cz,z);
    float d2 = __fadd_rn(__fadd_rn(__fmul_rn(dx,dx), __fmul_rn(dy,dy)), __fmul_rn(dz,dz));
    bool within = d2 < R2;
    unsigned long long m = __ballot(within);
    int pre  = __popcll(m & ((1ull << lane) - 1ull));
    int slot = count + pre;
    if (within && slot < NS) gid[slot] = i;
    count += __popcll(m);
  }
  __syncthreads();
  float* grow = gf + (size_t)bs * NS * CIN;
  for (int n = 0; n < NS; n++){
    int gi = gid[n];
    float* row = grow + n * CIN;
    if (gi < 0){
      row[lane] = 0.0f;
      if (lane < CIN - 64) row[64 + lane] = 0.0f;
    } else {
      float gx = X[gi*3+0], gy = X[gi*3+1], gz = X[gi*3+2];
      float v;
      if      (lane == 0) v = gx;
      else if (lane == 1) v = gy;
      else if (lane == 2) v = gz;
      else if (lane == 3) v = __fsub_rn(gx, cx);
      else if (lane == 4) v = __fsub_rn(gy, cy);
      else if (lane == 5) v = __fsub_rn(gz, cz);
      else                v = F[(size_t)gi * CF + (lane - 6)];
      row[lane] = v;
      if (lane < CIN - 64) row[64 + lane] = F[(size_t)gi * CF + 58 + lane];
    }
  }
}

// ---------------------------------------------------------------------------
// Kernel 3: BN1 statistics. thread <-> (row, v). Per-channel (H1=32)
// sum & sumsq accumulated via wave reduce + per-block double atomics.
// ---------------------------------------------------------------------------
__global__ __launch_bounds__(256) void k_stats1(const float* __restrict__ gf,
                                                const float* __restrict__ xyz,
                                                const int*   __restrict__ mc_idx,
                                                const float* __restrict__ W1_0,
                                                const float* __restrict__ b1_0,
                                                double* __restrict__ stats){
  __shared__ float W10[H1*13];
  __shared__ float b10[H1];
  __shared__ float mcs[NB][VV][3];
  __shared__ float part[4][64];
  const int t = threadIdx.x;
  for (int i = t; i < H1*13; i += 256) W10[i] = W1_0[i];
  if (t < H1) b10[t] = b1_0[t];
  if (t < NB*VV*3){
    int b_ = t / (VV*3), r = t % (VV*3), vv = r / 3, c = r % 3;
    mcs[b_][vv][c] = xyz[(size_t)b_ * NPTS * 3 + (size_t)mc_idx[vv] * 3 + c];
  }
  __syncthreads();
  const int tid = blockIdx.x * 256 + t;
  const int row = tid >> 3, v = tid & 7;
  const int b = row >> 15;                      // S*NS = 32768
  const float* g = gf + (size_t)row * CIN;
  float gx = g[0], gy = g[1], gz = g[2];
  float mx = mcs[b][v][0], my = mcs[b][v][1], mz = mcs[b][v][2];
  float ax = __fsub_rn(gx,mx), ay = __fsub_rn(gy,my), az = __fsub_rn(gz,mz);
  float eu = sqrtf(__fadd_rn(__fadd_rn(__fmul_rn(ax,ax), __fmul_rn(ay,ay)), __fmul_rn(az,az)));
  float rel[13] = {-ax,-ay,-az, ax,ay,az, eu, gx,gy,gz, mx,my,mz};
  float a1[H1];
#pragma unroll
  for (int h = 0; h < H1; h++){
    float acc = b10[h];
#pragma unroll
    for (int i = 0; i < 13; i++) acc = fmaf(rel[i], W10[h*13+i], acc);
    a1[h] = acc;
  }
  const int lane = t & 63, wid = t >> 6;
  for (int h = 0; h < H1; h++){
    float r1 = a1[h], r2 = a1[h]*a1[h];
#pragma unroll
    for (int off = 32; off >= 1; off >>= 1){
      r1 += __shfl_xor(r1, off);
      r2 += __shfl_xor(r2, off);
    }
    if (lane == 0){ part[wid][h] = r1; part[wid][h+32] = r2; }
  }
  __syncthreads();
  if (t < 64){
    float s = part[0][t] + part[1][t] + part[2][t] + part[3][t];
    atomicAdd(&stats[t], (double)s);
  }
}

__global__ void k_fin1(const double* __restrict__ st, const float* __restrict__ g1,
                       const float* __restrict__ be1, float* __restrict__ AB){
  int t = threadIdx.x;
  if (t < H1){
    double m   = st[t] / 524288.0;
    double var = st[t+32] / 524288.0 - m*m;
    double inv = 1.0 / sqrt(var + 1e-5);
    double A   = (double)g1[t] * inv;
    AB[t]      = (float)A;
    AB[t+H1]   = (float)((double)be1[t] - m*A);
  }
}

// ---------------------------------------------------------------------------
// Kernel 4: MLP1 (recompute a1, BN+gelu, x W1_1) + gumbel softmax + agg -> gf2
// lane <-> (row, v): 8 lanes per row; softmax over v via __shfl_xor(1,2,4).
// ---------------------------------------------------------------------------
__global__ __launch_bounds__(256) void k_mlp1(const float* __restrict__ gf,
                                              const float* __restrict__ gum,
                                              const float* __restrict__ xyz,
                                              const int*   __restrict__ mc_idx,
                                              const float* __restrict__ W1_0,
                                              const float* __restrict__ b1_0,
                                              const float* __restrict__ AB1,
                                              const float* __restrict__ W1_1,
                                              const float* __restrict__ b1_1,
                                              float* __restrict__ gf2){
  __shared__ float W10[H1*13];
  __shared__ float W11[CIN*H1];
  __shared__ float b10[H1], A1s[H1], B1s[H1];
  __shared__ float b11[CIN];
  __shared__ float mcs[NB][VV][3];
  const int t = threadIdx.x;
  for (int i = t; i < H1*13;  i += 256) W10[i] = W1_0[i];
  for (int i = t; i < CIN*H1; i += 256) W11[i] = W1_1[i];
  if (t < H1){ b10[t] = b1_0[t]; A1s[t] = AB1[t]; B1s[t] = AB1[t+H1]; }
  if (t < CIN) b11[t] = b1_1[t];
  if (t < NB*VV*3){
    int b_ = t / (VV*3), r = t % (VV*3), vv = r / 3, c = r % 3;
    mcs[b_][vv][c] = xyz[(size_t)b_ * NPTS * 3 + (size_t)mc_idx[vv] * 3 + c];
  }
  __syncthreads();
  const int tid = blockIdx.x * 256 + t;
  const int row = tid >> 3, v = tid & 7;
  const int b = row >> 15;
  const float* g = gf + (size_t)row * CIN;
  float gx = g[0], gy = g[1], gz = g[2];
  float mx = mcs[b][v][0], my = mcs[b][v][1], mz = mcs[b][v][2];
  float ax = __fsub_rn(gx,mx), ay = __fsub_rn(gy,my), az = __fsub_rn(gz,mz);
  float eu = sqrtf(__fadd_rn(__fadd_rn(__fmul_rn(ax,ax), __fmul_rn(ay,ay)), __fmul_rn(az,az)));
  float rel[13] = {-ax,-ay,-az, ax,ay,az, eu, gx,gy,gz, mx,my,mz};
  float a1g[H1];
#pragma unroll
  for (int h = 0; h < H1; h++){
    float acc = b10[h];
#pragma unroll
    for (int i = 0; i < 13; i++) acc = fmaf(rel[i], W10[h*13+i], acc);
    float x = fmaf(A1s[h], acc, B1s[h]);
    a1g[h] = gelu_f(x);
  }
  const float* gu = gum + (size_t)row * CIN * VV + v;
  for (int c = 0; c < CIN; c++){
    float a2 = b11[c];
#pragma unroll
    for (int h = 0; h < H1; h++) a2 = fmaf(a1g[h], W11[c*H1+h], a2);
    float gfv  = g[c];
    float prod = gfv * a2;
    float u    = gu[c*VV];
    float gg   = -__logf(-__logf(u));
    float tt   = prod + gg;
    float m8   = tt;
#pragma unroll
    for (int m = 1; m < 8; m <<= 1) m8 = fmaxf(m8, __shfl_xor(m8, m));
    float e  = __expf(tt - m8);
    float s1 = e, s2 = e * prod;
#pragma unroll
    for (int m = 1; m < 8; m <<= 1){ s1 += __shfl_xor(s1, m); s2 += __shfl_xor(s2, m); }
    if (v == 0) gf2[(size_t)row * CIN + c] = s2 / s1 + gfv;
  }
}

// ---------------------------------------------------------------------------
// Kernel 5: w_pre = gf2 @ W2_0^T + b2_0 (stored), res = gf @ Wr^T + br (stored),
// plus BN2 per-channel stats. thread <-> (cout, row-half); weights in regs.
// ---------------------------------------------------------------------------
__global__ __launch_bounds__(256) void k_wpre(const float* __restrict__ gf2,
                                              const float* __restrict__ gf,
                                              const float* __restrict__ W2_0,
                                              const float* __restrict__ b2_0,
                                              const float* __restrict__ Wr,
                                              const float* __restrict__ br,
                                              float* __restrict__ wpre,
                                              float* __restrict__ resb,
                                              double* __restrict__ stats2){
  const int t = threadIdx.x;
  const int c = t & 127, rh = t >> 7;
  float w0[CIN], wr[CIN];
#pragma unroll
  for (int i = 0; i < CIN; i++) w0[i] = W2_0[(size_t)c*CIN + i];
#pragma unroll
  for (int i = 0; i < CIN; i++) wr[i] = Wr[(size_t)c*CIN + i];
  const float bias0 = b2_0[c], biasr = br[c];
  const int base = blockIdx.x * 32;
  float s1 = 0.f, s2 = 0.f;
  for (int j = 0; j < 16; j++){
    int row = base + rh + 2*j;
    const float* g2r = gf2 + (size_t)row * CIN;
    const float* gr  = gf  + (size_t)row * CIN;
    float acc = bias0, accr = biasr;
#pragma unroll
    for (int i = 0; i < CIN; i++){
      float a = g2r[i], b = gr[i];
      acc  = fmaf(a, w0[i], acc);
      accr = fmaf(b, wr[i], accr);
    }
    wpre[(size_t)row*COUT + c] = acc;
    resb[(size_t)row*COUT + c] = accr;
    s1 += acc; s2 += acc*acc;
  }
  __shared__ float buf[256];
  buf[t] = s1; __syncthreads();
  if (t < 128) atomicAdd(&stats2[c], (double)(buf[t] + buf[t+128]));
  __syncthreads();
  buf[t] = s2; __syncthreads();
  if (t < 128) atomicAdd(&stats2[128+c], (double)(buf[t] + buf[t+128]));
}

__global__ void k_fin2(const double* __restrict__ st, const float* __restrict__ g2,
                       const float* __restrict__ be2, float* __restrict__ AB){
  int t = threadIdx.x;
  if (t < COUT){
    double m   = st[t] / 65536.0;
    double var = st[t+128] / 65536.0 - m*m;
    double inv = 1.0 / sqrt(var + 1e-5);
    double A   = (double)g2[t] * inv;
    AB[t]      = (float)A;
    AB[t+COUT] = (float)((double)be2[t] - m*A);
  }
}

// ---------------------------------------------------------------------------
// Kernel 6: final. gb = gelu(BN2(w_pre)); w2 = gb @ W2_1^T + b2_1;
// new_f = gelu(w2 + res); out = max_n + sum_n. Block handles 2 (b,s).
// W2_1 row per thread in registers; gb exchanged through LDS.
// ---------------------------------------------------------------------------
__global__ __launch_bounds__(512) void k_final(const float* __restrict__ wpre,
                                               const float* __restrict__ resb,
                                               const float* __restrict__ W2_1,
                                               const float* __restrict__ b2_1,
                                               const float* __restrict__ AB2,
                                               float* __restrict__ out){
  __shared__ float gbuf[4][COUT];
  __shared__ float pm[512], ps[512];
  const int t = threadIdx.x;
  const int o = t & 127, g = t >> 7;
  float w21[COUT];
#pragma unroll
  for (int k = 0; k < COUT; k++) w21[k] = W2_1[(size_t)o*COUT + k];
  const float A2 = AB2[o], B2 = AB2[COUT+o], b21 = b2_1[o];
  const int bs = blockIdx.x * 2 + (g >> 1);
  const int rp = g & 1;
  float vmax = -3.4e38f, vsum = 0.f;
  for (int j = 0; j < 16; j++){
    int n = rp + 2*j;
    int row = bs * NS + n;
    float w  = wpre[(size_t)row*COUT + o];
    float x  = fmaf(A2, w, B2);
    gbuf[g][o] = gelu_f(x);
    __syncthreads();
    float w2 = b21;
#pragma unroll
    for (int k = 0; k < COUT; k++) w2 = fmaf(gbuf[g][k], w21[k], w2);
    float y  = w2 + resb[(size_t)row*COUT + o];
    float nf = gelu_f(y);
    vmax = fmaxf(vmax, nf);
    vsum += nf;
    __syncthreads();
  }
  pm[t] = vmax; ps[t] = vsum;
  __syncthreads();
  if (rp == 0){
    float m = fmaxf(pm[t], pm[t+128]);
    float s = ps[t] + ps[t+128];
    out[(size_t)bs*COUT + o] = m + s;
  }
}

// ---------------------------------------------------------------------------
extern "C" void kernel_launch(void* const* d_in, const int* in_sizes, int n_in,
                              void* d_out, int out_size, void* d_ws, size_t ws_size,
                              hipStream_t stream) {
  (void)in_sizes; (void)n_in; (void)out_size; (void)ws_size;
  const float* xyz   = (const float*)d_in[0];
  const float* f     = (const float*)d_in[1];
  const int*   mcid  = (const int*)  d_in[2];
  const float* gum   = (const float*)d_in[3];
  const float* W1_0  = (const float*)d_in[4];
  const float* b1_0  = (const float*)d_in[5];
  const float* g1_0  = (const float*)d_in[6];
  const float* be1_0 = (const float*)d_in[7];
  const float* W1_1  = (const float*)d_in[8];
  const float* b1_1  = (const float*)d_in[9];
  const float* W2_0  = (const float*)d_in[10];
  const float* b2_0  = (const float*)d_in[11];
  const float* g2_0  = (const float*)d_in[12];
  const float* be2_0 = (const float*)d_in[13];
  const float* W2_1  = (const float*)d_in[14];
  const float* b2_1  = (const float*)d_in[15];
  const float* Wr    = (const float*)d_in[16];
  const float* br    = (const float*)d_in[17];

  float* out     = (float*)d_out;
  float* new_xyz = out + (size_t)NB * SSAMP * COUT;   // tail of d_out

  char*   ws    = (char*)d_ws;
  double* stats = (double*)ws;                 // [0..63] BN1, [64..319] BN2
  float*  AB1   = (float*)(ws + 2560);         // 32 A + 32 B
  float*  AB2   = AB1 + 64;                    // 128 A + 128 B
  float*  gfb   = (float*)(ws + 4096);
  const size_t ROWS = (size_t)NB * SSAMP * NS; // 65536
  float*  gf2   = gfb + ROWS * CIN;
  float*  wpre  = gf2 + ROWS * CIN;
  float*  resb  = wpre + ROWS * COUT;

  hipMemsetAsync(d_ws, 0, 2560, stream);

  const size_t fps_lds = (size_t)NPTS * 3 * sizeof(float) + 2 * 4 * sizeof(unsigned long long);
  k_fps   <<<NB,              256, fps_lds, stream>>>(xyz, new_xyz);
  k_ballq <<<NB*SSAMP,        64,   0, stream>>>(xyz, f, new_xyz, gfb);
  k_stats1<<<2048,            256,  0, stream>>>(gfb, xyz, mcid, W1_0, b1_0, stats);
  k_fin1  <<<1,               64,   0, stream>>>(stats, g1_0, be1_0, AB1);
  k_mlp1  <<<2048,            256,  0, stream>>>(gfb, gum, xyz, mcid, W1_0, b1_0, AB1, W1_1, b1_1, gf2);
  k_wpre  <<<2048,            256,  0, stream>>>(gf2, gfb, W2_0, b2_0, Wr, br, wpre, resb, stats + 64);
  k_fin2  <<<1,               128,  0, stream>>>(stats + 64, g2_0, be2_0, AB2);
  k_final <<<1024,            512,  0, stream>>>(wpre, resb, W2_1, b2_1, AB2, out);
}

// Round 5
// 2045.564 us; speedup vs baseline: 1.7493x; 1.0015x over previous
//
#include <hip/hip_runtime.h>
#include <math.h>

#define NB    2
#define NPTS  8192
#define SSAMP 1024
#define NS    32
#define VV    8
#define CF    64
#define CIN   70
#define COUT  128
#define H1    32

__device__ __forceinline__ float gelu_f(float x){
  return 0.5f*x*(1.0f + erff(x*0.70710678118654752440f));
}

// ---------------------------------------------------------------------------
// Kernel 1: farthest point sampling, v4 (= v3 + launch_bounds(256,1)).
// 256 threads (4 waves) per batch, 32 points/thread in registers.
// (256,1): min 1 wave/EU -> VGPR cap ~512, so px/py/pz/dmin[32] (128 regs)
// stay register-resident (v3 spilled at VGPR_Count=104).
// Per step: LDS broadcast center -> 32 reg-resident dist updates with
// (cmp,cndmask,max) argmax tracking -> 6-level wave shuffle reduce ->
// 4 u64 partials in double-buffered LDS -> ONE barrier -> 2-level tree.
// Distances use rn intrinsics (no fma) to bit-match the reference.
// ---------------------------------------------------------------------------
__global__ __launch_bounds__(256, 1) void k_fps(const float* __restrict__ xyz,
                                                float* __restrict__ new_xyz){
  extern __shared__ unsigned char dynls[];
  float* sxyz = (float*)dynls;                                   // [NPTS*3] interleaved
  unsigned long long* part = (unsigned long long*)(sxyz + NPTS*3); // [2][4]

  const int b = blockIdx.x;
  const int t = threadIdx.x;
  const float* X = xyz + (size_t)b * NPTS * 3;
  float px[32], py[32], pz[32], dmin[32];
#pragma unroll
  for (int k = 0; k < 32; k++){
    int i = t + k * 256;
    float x = X[i*3+0], y = X[i*3+1], z = X[i*3+2];
    px[k] = x; py[k] = y; pz[k] = z;
    sxyz[i*3+0] = x; sxyz[i*3+1] = y; sxyz[i*3+2] = z;
    dmin[k] = 3.4e38f;
  }
  __syncthreads();

  int last = 0;
  const int lane = t & 63, wid = t >> 6;
  int pb = 0;
  float* orow = new_xyz + (size_t)b * SSAMP * 3;
  for (int s = 0; s < SSAMP; s++){
    float cx = sxyz[last*3+0], cy = sxyz[last*3+1], cz = sxyz[last*3+2];
    if (t == 0){ orow[0] = cx; orow[1] = cy; orow[2] = cz; orow += 3; }
    float best = -1.0f; int bk = 0;
#pragma unroll
    for (int k = 0; k < 32; k++){
      float dx = __fsub_rn(px[k], cx);
      float dy = __fsub_rn(py[k], cy);
      float dz = __fsub_rn(pz[k], cz);
      float d  = __fadd_rn(__fadd_rn(__fmul_rn(dx,dx), __fmul_rn(dy,dy)), __fmul_rn(dz,dz));
      d = fminf(dmin[k], d);
      dmin[k] = d;
      bk   = (d > best) ? k : bk;      // ascending k + strict > = first max
      best = fmaxf(best, d);
    }
    int bi = t | (bk << 8);            // true point index (t<256)
#pragma unroll
    for (int off = 32; off >= 1; off >>= 1){
      float ov = __shfl_down(best, off);
      int   oi = __shfl_down(bi,   off);
      bool take = (ov > best) || (ov == best && oi < bi);
      best = take ? ov : best;
      bi   = take ? oi : bi;
    }
    if (lane == 0){
      part[pb*4 + wid] = ((unsigned long long)__float_as_uint(best) << 32)
                       | (unsigned long long)(~(unsigned)bi);
    }
    __syncthreads();
    unsigned long long v0 = part[pb*4 + 0];
    unsigned long long v1 = part[pb*4 + 1];
    unsigned long long v2 = part[pb*4 + 2];
    unsigned long long v3 = part[pb*4 + 3];
    unsigned long long m0 = (v0 > v1) ? v0 : v1;
    unsigned long long m1 = (v2 > v3) ? v2 : v3;
    unsigned long long m  = (m0 > m1) ? m0 : m1;
    last = (int)(~(unsigned)(m & 0xFFFFFFFFull));
    pb ^= 1;
  }
}

// ---------------------------------------------------------------------------
// Kernel 2: ball query + build gf (B,S,NS,CIN) = [grouped_xyz, local, feat].
// One wave per (b,s). Masked slots get zeros (matches reference semantics,
// which also zeroes downstream agg for them automatically).
// ---------------------------------------------------------------------------
__global__ __launch_bounds__(64) void k_ballq(const float* __restrict__ xyz,
                                              const float* __restrict__ feat,
                                              const float* __restrict__ new_xyz,
                                              float* __restrict__ gf){
  const int bs = blockIdx.x;          // b*S + s
  const int b  = bs >> 10;
  const int lane = threadIdx.x;
  const float* X = xyz  + (size_t)b * NPTS * 3;
  const float* F = feat + (size_t)b * NPTS * CF;
  const float cx = new_xyz[bs*3+0], cy = new_xyz[bs*3+1], cz = new_xyz[bs*3+2];
  __shared__ int gid[NS];
  if (lane < NS) gid[lane] = -1;
  __syncthreads();
  const float R2 = (float)(0.2 * 0.2);   // matches JAX double->f32 demotion
  int count = 0;
  for (int base = 0; base < NPTS && count < NS; base += 64){
    int i = base + lane;
    float x = X[i*3+0], y = X[i*3+1], z = X[i*3+2];
    float dx = __fsub_rn(cx,x), dy = __fsub_rn(cy,y), dz = __fsub_rn(cz,z);
    float d2 = __fadd_rn(__fadd_rn(__fmul_rn(dx,dx), __fmul_rn(dy,dy)), __fmul_rn(dz,dz));
    bool within = d2 < R2;
    unsigned long long m = __ballot(within);
    int pre  = __popcll(m & ((1ull << lane) - 1ull));
    int slot = count + pre;
    if (within && slot < NS) gid[slot] = i;
    count += __popcll(m);
  }
  __syncthreads();
  float* grow = gf + (size_t)bs * NS * CIN;
  for (int n = 0; n < NS; n++){
    int gi = gid[n];
    float* row = grow + n * CIN;
    if (gi < 0){
      row[lane] = 0.0f;
      if (lane < CIN - 64) row[64 + lane] = 0.0f;
    } else {
      float gx = X[gi*3+0], gy = X[gi*3+1], gz = X[gi*3+2];
      float v;
      if      (lane == 0) v = gx;
      else if (lane == 1) v = gy;
      else if (lane == 2) v = gz;
      else if (lane == 3) v = __fsub_rn(gx, cx);
      else if (lane == 4) v = __fsub_rn(gy, cy);
      else if (lane == 5) v = __fsub_rn(gz, cz);
      else                v = F[(size_t)gi * CF + (lane - 6)];
      row[lane] = v;
      if (lane < CIN - 64) row[64 + lane] = F[(size_t)gi * CF + 58 + lane];
    }
  }
}

// ---------------------------------------------------------------------------
// Kernel 3: BN1 statistics. thread <-> (row, v). Per-channel (H1=32)
// sum & sumsq accumulated via wave reduce + per-block double atomics.
// ---------------------------------------------------------------------------
__global__ __launch_bounds__(256) void k_stats1(const float* __restrict__ gf,
                                                const float* __restrict__ xyz,
                                                const int*   __restrict__ mc_idx,
                                                const float* __restrict__ W1_0,
                                                const float* __restrict__ b1_0,
                                                double* __restrict__ stats){
  __shared__ float W10[H1*13];
  __shared__ float b10[H1];
  __shared__ float mcs[NB][VV][3];
  __shared__ float part[4][64];
  const int t = threadIdx.x;
  for (int i = t; i < H1*13; i += 256) W10[i] = W1_0[i];
  if (t < H1) b10[t] = b1_0[t];
  if (t < NB*VV*3){
    int b_ = t / (VV*3), r = t % (VV*3), vv = r / 3, c = r % 3;
    mcs[b_][vv][c] = xyz[(size_t)b_ * NPTS * 3 + (size_t)mc_idx[vv] * 3 + c];
  }
  __syncthreads();
  const int tid = blockIdx.x * 256 + t;
  const int row = tid >> 3, v = tid & 7;
  const int b = row >> 15;                      // S*NS = 32768
  const float* g = gf + (size_t)row * CIN;
  float gx = g[0], gy = g[1], gz = g[2];
  float mx = mcs[b][v][0], my = mcs[b][v][1], mz = mcs[b][v][2];
  float ax = __fsub_rn(gx,mx), ay = __fsub_rn(gy,my), az = __fsub_rn(gz,mz);
  float eu = sqrtf(__fadd_rn(__fadd_rn(__fmul_rn(ax,ax), __fmul_rn(ay,ay)), __fmul_rn(az,az)));
  float rel[13] = {-ax,-ay,-az, ax,ay,az, eu, gx,gy,gz, mx,my,mz};
  float a1[H1];
#pragma unroll
  for (int h = 0; h < H1; h++){
    float acc = b10[h];
#pragma unroll
    for (int i = 0; i < 13; i++) acc = fmaf(rel[i], W10[h*13+i], acc);
    a1[h] = acc;
  }
  const int lane = t & 63, wid = t >> 6;
  for (int h = 0; h < H1; h++){
    float r1 = a1[h], r2 = a1[h]*a1[h];
#pragma unroll
    for (int off = 32; off >= 1; off >>= 1){
      r1 += __shfl_xor(r1, off);
      r2 += __shfl_xor(r2, off);
    }
    if (lane == 0){ part[wid][h] = r1; part[wid][h+32] = r2; }
  }
  __syncthreads();
  if (t < 64){
    float s = part[0][t] + part[1][t] + part[2][t] + part[3][t];
    atomicAdd(&stats[t], (double)s);
  }
}

__global__ void k_fin1(const double* __restrict__ st, const float* __restrict__ g1,
                       const float* __restrict__ be1, float* __restrict__ AB){
  int t = threadIdx.x;
  if (t < H1){
    double m   = st[t] / 524288.0;
    double var = st[t+32] / 524288.0 - m*m;
    double inv = 1.0 / sqrt(var + 1e-5);
    double A   = (double)g1[t] * inv;
    AB[t]      = (float)A;
    AB[t+H1]   = (float)((double)be1[t] - m*A);
  }
}

// ---------------------------------------------------------------------------
// Kernel 4: MLP1 (recompute a1, BN+gelu, x W1_1) + gumbel softmax + agg -> gf2
// lane <-> (row, v): 8 lanes per row; softmax over v via __shfl_xor(1,2,4).
// ---------------------------------------------------------------------------
__global__ __launch_bounds__(256) void k_mlp1(const float* __restrict__ gf,
                                              const float* __restrict__ gum,
                                              const float* __restrict__ xyz,
                                              const int*   __restrict__ mc_idx,
                                              const float* __restrict__ W1_0,
                                              const float* __restrict__ b1_0,
                                              const float* __restrict__ AB1,
                                              const float* __restrict__ W1_1,
                                              const float* __restrict__ b1_1,
                                              float* __restrict__ gf2){
  __shared__ float W10[H1*13];
  __shared__ float W11[CIN*H1];
  __shared__ float b10[H1], A1s[H1], B1s[H1];
  __shared__ float b11[CIN];
  __shared__ float mcs[NB][VV][3];
  const int t = threadIdx.x;
  for (int i = t; i < H1*13;  i += 256) W10[i] = W1_0[i];
  for (int i = t; i < CIN*H1; i += 256) W11[i] = W1_1[i];
  if (t < H1){ b10[t] = b1_0[t]; A1s[t] = AB1[t]; B1s[t] = AB1[t+H1]; }
  if (t < CIN) b11[t] = b1_1[t];
  if (t < NB*VV*3){
    int b_ = t / (VV*3), r = t % (VV*3), vv = r / 3, c = r % 3;
    mcs[b_][vv][c] = xyz[(size_t)b_ * NPTS * 3 + (size_t)mc_idx[vv] * 3 + c];
  }
  __syncthreads();
  const int tid = blockIdx.x * 256 + t;
  const int row = tid >> 3, v = tid & 7;
  const int b = row >> 15;
  const float* g = gf + (size_t)row * CIN;
  float gx = g[0], gy = g[1], gz = g[2];
  float mx = mcs[b][v][0], my = mcs[b][v][1], mz = mcs[b][v][2];
  float ax = __fsub_rn(gx,mx), ay = __fsub_rn(gy,my), az = __fsub_rn(gz,mz);
  float eu = sqrtf(__fadd_rn(__fadd_rn(__fmul_rn(ax,ax), __fmul_rn(ay,ay)), __fmul_rn(az,az)));
  float rel[13] = {-ax,-ay,-az, ax,ay,az, eu, gx,gy,gz, mx,my,mz};
  float a1g[H1];
#pragma unroll
  for (int h = 0; h < H1; h++){
    float acc = b10[h];
#pragma unroll
    for (int i = 0; i < 13; i++) acc = fmaf(rel[i], W10[h*13+i], acc);
    float x = fmaf(A1s[h], acc, B1s[h]);
    a1g[h] = gelu_f(x);
  }
  const float* gu = gum + (size_t)row * CIN * VV + v;
  for (int c = 0; c < CIN; c++){
    float a2 = b11[c];
#pragma unroll
    for (int h = 0; h < H1; h++) a2 = fmaf(a1g[h], W11[c*H1+h], a2);
    float gfv  = g[c];
    float prod = gfv * a2;
    float u    = gu[c*VV];
    float gg   = -__logf(-__logf(u));
    float tt   = prod + gg;
    float m8   = tt;
#pragma unroll
    for (int m = 1; m < 8; m <<= 1) m8 = fmaxf(m8, __shfl_xor(m8, m));
    float e  = __expf(tt - m8);
    float s1 = e, s2 = e * prod;
#pragma unroll
    for (int m = 1; m < 8; m <<= 1){ s1 += __shfl_xor(s1, m); s2 += __shfl_xor(s2, m); }
    if (v == 0) gf2[(size_t)row * CIN + c] = s2 / s1 + gfv;
  }
}

// ---------------------------------------------------------------------------
// Kernel 5: w_pre = gf2 @ W2_0^T + b2_0 (stored), res = gf @ Wr^T + br (stored),
// plus BN2 per-channel stats. thread <-> (cout, row-half); weights in regs.
// (256,2): VGPR cap 256 so w0[70]+wr[70] stay register-resident.
// ---------------------------------------------------------------------------
__global__ __launch_bounds__(256, 2) void k_wpre(const float* __restrict__ gf2,
                                                 const float* __restrict__ gf,
                                                 const float* __restrict__ W2_0,
                                                 const float* __restrict__ b2_0,
                                                 const float* __restrict__ Wr,
                                                 const float* __restrict__ br,
                                                 float* __restrict__ wpre,
                                                 float* __restrict__ resb,
                                                 double* __restrict__ stats2){
  const int t = threadIdx.x;
  const int c = t & 127, rh = t >> 7;
  float w0[CIN], wr[CIN];
#pragma unroll
  for (int i = 0; i < CIN; i++) w0[i] = W2_0[(size_t)c*CIN + i];
#pragma unroll
  for (int i = 0; i < CIN; i++) wr[i] = Wr[(size_t)c*CIN + i];
  const float bias0 = b2_0[c], biasr = br[c];
  const int base = blockIdx.x * 32;
  float s1 = 0.f, s2 = 0.f;
  for (int j = 0; j < 16; j++){
    int row = base + rh + 2*j;
    const float* g2r = gf2 + (size_t)row * CIN;
    const float* gr  = gf  + (size_t)row * CIN;
    float acc = bias0, accr = biasr;
#pragma unroll
    for (int i = 0; i < CIN; i++){
      float a = g2r[i], b = gr[i];
      acc  = fmaf(a, w0[i], acc);
      accr = fmaf(b, wr[i], accr);
    }
    wpre[(size_t)row*COUT + c] = acc;
    resb[(size_t)row*COUT + c] = accr;
    s1 += acc; s2 += acc*acc;
  }
  __shared__ float buf[256];
  buf[t] = s1; __syncthreads();
  if (t < 128) atomicAdd(&stats2[c], (double)(buf[t] + buf[t+128]));
  __syncthreads();
  buf[t] = s2; __syncthreads();
  if (t < 128) atomicAdd(&stats2[128+c], (double)(buf[t] + buf[t+128]));
}

__global__ void k_fin2(const double* __restrict__ st, const float* __restrict__ g2,
                       const float* __restrict__ be2, float* __restrict__ AB){
  int t = threadIdx.x;
  if (t < COUT){
    double m   = st[t] / 65536.0;
    double var = st[t+128] / 65536.0 - m*m;
    double inv = 1.0 / sqrt(var + 1e-5);
    double A   = (double)g2[t] * inv;
    AB[t]      = (float)A;
    AB[t+COUT] = (float)((double)be2[t] - m*A);
  }
}

// ---------------------------------------------------------------------------
// Kernel 6: final. gb = gelu(BN2(w_pre)); w2 = gb @ W2_1^T + b2_1;
// new_f = gelu(w2 + res); out = max_n + sum_n. Block handles 2 (b,s).
// (512,2): VGPR cap 256 so w21[128] stays register-resident (was spilled
// at VGPR_Count=84 -> 8KB scratch re-read per thread + 20ms first-touch).
// ---------------------------------------------------------------------------
__global__ __launch_bounds__(512, 2) void k_final(const float* __restrict__ wpre,
                                                  const float* __restrict__ resb,
                                                  const float* __restrict__ W2_1,
                                                  const float* __restrict__ b2_1,
                                                  const float* __restrict__ AB2,
                                                  float* __restrict__ out){
  __shared__ float gbuf[4][COUT];
  __shared__ float pm[512], ps[512];
  const int t = threadIdx.x;
  const int o = t & 127, g = t >> 7;
  float w21[COUT];
#pragma unroll
  for (int k = 0; k < COUT; k++) w21[k] = W2_1[(size_t)o*COUT + k];
  const float A2 = AB2[o], B2 = AB2[COUT+o], b21 = b2_1[o];
  const int bs = blockIdx.x * 2 + (g >> 1);
  const int rp = g & 1;
  float vmax = -3.4e38f, vsum = 0.f;
  for (int j = 0; j < 16; j++){
    int n = rp + 2*j;
    int row = bs * NS + n;
    float w  = wpre[(size_t)row*COUT + o];
    float x  = fmaf(A2, w, B2);
    gbuf[g][o] = gelu_f(x);
    __syncthreads();
    float w2 = b21;
#pragma unroll
    for (int k = 0; k < COUT; k++) w2 = fmaf(gbuf[g][k], w21[k], w2);
    float y  = w2 + resb[(size_t)row*COUT + o];
    float nf = gelu_f(y);
    vmax = fmaxf(vmax, nf);
    vsum += nf;
    __syncthreads();
  }
  pm[t] = vmax; ps[t] = vsum;
  __syncthreads();
  if (rp == 0){
    float m = fmaxf(pm[t], pm[t+128]);
    float s = ps[t] + ps[t+128];
    out[(size_t)bs*COUT + o] = m + s;
  }
}

// ---------------------------------------------------------------------------
extern "C" void kernel_launch(void* const* d_in, const int* in_sizes, int n_in,
                              void* d_out, int out_size, void* d_ws, size_t ws_size,
                              hipStream_t stream) {
  (void)in_sizes; (void)n_in; (void)out_size; (void)ws_size;
  const float* xyz   = (const float*)d_in[0];
  const float* f     = (const float*)d_in[1];
  const int*   mcid  = (const int*)  d_in[2];
  const float* gum   = (const float*)d_in[3];
  const float* W1_0  = (const float*)d_in[4];
  const float* b1_0  = (const float*)d_in[5];
  const float* g1_0  = (const float*)d_in[6];
  const float* be1_0 = (const float*)d_in[7];
  const float* W1_1  = (const float*)d_in[8];
  const float* b1_1  = (const float*)d_in[9];
  const float* W2_0  = (const float*)d_in[10];
  const float* b2_0  = (const float*)d_in[11];
  const float* g2_0  = (const float*)d_in[12];
  const float* be2_0 = (const float*)d_in[13];
  const float* W2_1  = (const float*)d_in[14];
  const float* b2_1  = (const float*)d_in[15];
  const float* Wr    = (const float*)d_in[16];
  const float* br    = (const float*)d_in[17];

  float* out     = (float*)d_out;
  float* new_xyz = out + (size_t)NB * SSAMP * COUT;   // tail of d_out

  char*   ws    = (char*)d_ws;
  double* stats = (double*)ws;                 // [0..63] BN1, [64..319] BN2
  float*  AB1   = (float*)(ws + 2560);         // 32 A + 32 B
  float*  AB2   = AB1 + 64;                    // 128 A + 128 B
  float*  gfb   = (float*)(ws + 4096);
  const size_t ROWS = (size_t)NB * SSAMP * NS; // 65536
  float*  gf2   = gfb + ROWS * CIN;
  float*  wpre  = gf2 + ROWS * CIN;
  float*  resb  = wpre + ROWS * COUT;

  hipMemsetAsync(d_ws, 0, 2560, stream);

  const size_t fps_lds = (size_t)NPTS * 3 * sizeof(float) + 2 * 4 * sizeof(unsigned long long);
  k_fps   <<<NB,              256, fps_lds, stream>>>(xyz, new_xyz);
  k_ballq <<<NB*SSAMP,        64,   0, stream>>>(xyz, f, new_xyz, gfb);
  k_stats1<<<2048,            256,  0, stream>>>(gfb, xyz, mcid, W1_0, b1_0, stats);
  k_fin1  <<<1,               64,   0, stream>>>(stats, g1_0, be1_0, AB1);
  k_mlp1  <<<2048,            256,  0, stream>>>(gfb, gum, xyz, mcid, W1_0, b1_0, AB1, W1_1, b1_1, gf2);
  k_wpre  <<<2048,            256,  0, stream>>>(gf2, gfb, W2_0, b2_0, Wr, br, wpre, resb, stats + 64);
  k_fin2  <<<1,               128,  0, stream>>>(stats + 64, g2_0, be2_0, AB2);
  k_final <<<1024,            512,  0, stream>>>(wpre, resb, W2_1, b2_1, AB2, out);
}